// Round 9
// baseline (1525.579 us; speedup 1.0000x reference)
//
#include <hip/hip_runtime.h>
#include <stdint.h>

// ---------------- problem constants ----------------
#define T_TOKENS 4096
#define D_HID    2048
#define D_INT    4096
#define N_EXP    8
#define TOPK     4
#define NFLAT    (T_TOKENS*TOPK)      // 16384 routed pairs
#define BMT      256                  // M tile
#define MAXPAD   (NFLAT + N_EXP*BMT)  // 18432 worst-case padded rows
#define MT2      (MAXPAD/BMT)         // 72 M-tiles

// ---------------- ws layout (bytes) ----------------
#define OFF_PTOK 0ull
#define OFF_PWT  73728ull
#define OFF_CNT  147456ull
#define OFF_TOFF 147712ull
#define OFF_SEG  155904ull
#define OFF_XB   262144ull                  // 4096*2048*2 = 16,777,216
#define OFF_ACT  17039360ull                // 18432*4096*2 = 150,994,944
#define OFF_W    168034304ull               // max(wgu_b 256MB, wd_b 128MB)

typedef float f32x4   __attribute__((ext_vector_type(4)));
typedef float f32x16  __attribute__((ext_vector_type(16)));
typedef short bf16x8  __attribute__((ext_vector_type(8)));

__device__ __forceinline__ unsigned short f2bf(float f) {
    unsigned int u = __float_as_uint(f);
    u += 0x7fffu + ((u >> 16) & 1u);      // RNE
    return (unsigned short)(u >> 16);
}

__device__ __forceinline__ void gload_lds16(const void* g, void* l) {
    __builtin_amdgcn_global_load_lds((const __attribute__((address_space(1))) void*)g,
                                     (__attribute__((address_space(3))) void*)l,
                                     16, 0, 0);
}

// XCD-bijective chunk swizzle (m204)
__device__ __forceinline__ int xcd_logical(int hw, int nwg) {
    int q = nwg >> 3, r = nwg & 7;
    int xc = hw & 7, sl = hw >> 3;
    return (xc < r ? xc * (q + 1) : r * (q + 1) + (xc - r) * q) + sl;
}

// ---------------- prep: cast x -> bf16 + zero out (grid-stride) ----------------
__global__ void k_prep(const float* __restrict__ x, unsigned short* __restrict__ xb,
                       float* __restrict__ out) {
    const int N4 = T_TOKENS * D_HID / 4;             // 2,097,152
    for (int i = blockIdx.x * 256 + threadIdx.x; i < N4; i += 2048 * 256) {
        float4 v = ((const float4*)x)[i];
        ushort4 h;
        h.x = f2bf(v.x); h.y = f2bf(v.y); h.z = f2bf(v.z); h.w = f2bf(v.w);
        ((ushort4*)xb)[i] = h;
        ((float4*)out)[i] = make_float4(0.f, 0.f, 0.f, 0.f);
    }
}

// ---------------- fp32 -> bf16 cast (grid-stride, n4 float4s) ----------------
__global__ void k_cast(const float* __restrict__ src, unsigned short* __restrict__ dst, int n4) {
    for (int i = blockIdx.x * 256 + threadIdx.x; i < n4; i += 2048 * 256) {
        float4 v = ((const float4*)src)[i];
        ushort4 h;
        h.x = f2bf(v.x); h.y = f2bf(v.y); h.z = f2bf(v.z); h.w = f2bf(v.w);
        ((ushort4*)dst)[i] = h;
    }
}

// ---------------- routing: deterministic compaction ----------------
__global__ void k_count(const int* __restrict__ te, int* __restrict__ counts,
                        int* __restrict__ toff) {
    int e = blockIdx.x, t = threadIdx.x;
    int cnt = 0;
    int base = t * 64;
    for (int i = 0; i < 64; i++) cnt += (te[base + i] == e);
    __shared__ int s[256];
    s[t] = cnt; __syncthreads();
    int incl = cnt;
    for (int off = 1; off < 256; off <<= 1) {
        int tmp = (t >= off) ? s[t - off] : 0;
        __syncthreads();
        incl += tmp; s[t] = incl;
        __syncthreads();
    }
    toff[e * 256 + t] = incl - cnt;
    if (t == 255) counts[e] = incl;
}

__global__ void k_fill(const int* __restrict__ te, const float* __restrict__ tw,
                       const int* __restrict__ counts, const int* __restrict__ toff,
                       int* __restrict__ ptok, float* __restrict__ pwt, int* __restrict__ seg) {
    int e = blockIdx.x, t = threadIdx.x;
    int segs[9]; int a = 0;
    #pragma unroll
    for (int j = 0; j < 8; j++) { segs[j] = a; a += (counts[j] + BMT - 1) & ~(BMT - 1); }
    segs[8] = a;
    if (e == 0 && t == 0) { for (int j = 0; j < 9; j++) seg[j] = segs[j]; }
    int base = segs[e] + toff[e * 256 + t];
    int rank = 0;
    for (int i = t * 64; i < (t + 1) * 64; i++) {
        if (te[i] == e) { ptok[base + rank] = i >> 2; pwt[base + rank] = tw[i]; rank++; }
    }
    int cnt = counts[e], pc = (cnt + BMT - 1) & ~(BMT - 1);
    for (int i = cnt + t; i < pc; i += 256) { ptok[segs[e] + i] = -1; pwt[segs[e] + i] = 0.f; }
}

// =====================================================================
// Round-9 core: 32x32x16 MFMA (2495 TF ceiling vs 2075 for 16x16x32,
// m119) + 5-slot ring (160 KiB LDS, AITER-precedent) distance 4.
// 256x256 tile, 8 waves (2wr x 4wc), wave C = 128x64 = 4 m-frags x
// 2 n-frags of 32x32, acc = f32x16[4][2] (128 regs, unchanged).
// Slot = A 256x32 (16K) + B 256x32 (16K) = 32 KiB; 5 slots = 160 KiB.
// Per slot 2 phases (kk=0,1), each: [6 ds_read][stage 2 gloads][BAR]
// [lgkm0][SGB][prio1 8 MFMA prio0][BAR]. Same read count as r8
// (12 b128/wave/slot), MFMA serial term 1242 -> 1033 cyc/slot.
// Gates (in-order vmcnt retirement): steady vmcnt(12) = 16 outstanding
// (slots T+1..T+4), retire oldest 4 = slot T+1 done; tail 8/4/0.
// WAR: stage of slot T+4 -> phys (T-1)%5, issued after T-1's end-bar.
// Swizzle: phys chunk p of row r holds data chunk p^(r&3); stage src
// g=(l&3)^((l>>2)&3); read phys ((2kk+hi)^(l&3)), hi=l>>5, row=l&31
// (+32m). Bank audit: lanes 0-31 span-set {0,8,20,28}, lanes 32-63
// {4,12,16,24} -> balanced -> predicted 0 conflicts.
// Frag layouts (m74/m101/m119): A/B lane: row/col=l&31, k=8*hi+j;
// C/D: col=l&31, row=(reg&3)+8*(reg>>2)+4*hi.
// =====================================================================

#define MFMA8(AV, BV) \
    _Pragma("unroll") for (int m_ = 0; m_ < 4; ++m_) \
      _Pragma("unroll") for (int n_ = 0; n_ < 2; ++n_) \
        acc[m_][n_] = __builtin_amdgcn_mfma_f32_32x32x16_bf16(AV[m_], BV[n_], acc[m_][n_], 0, 0, 0);

#define GATE12 asm volatile("s_waitcnt vmcnt(12)" ::: "memory");
#define GATE8  asm volatile("s_waitcnt vmcnt(8)" ::: "memory");
#define GATE4  asm volatile("s_waitcnt vmcnt(4)" ::: "memory");
#define GATE0  asm volatile("s_waitcnt vmcnt(0)" ::: "memory");
#define GATEN

#define PH_A(DOSTAGE) \
  { \
    const char* pT = ldsc + cb * 32768; \
    _Pragma("unroll") for (int n_ = 0; n_ < 2; ++n_) \
        bfr[n_] = *(const bf16x8*)(pT + boff + n_ * 2048 + ch0); \
    _Pragma("unroll") for (int m_ = 0; m_ < 4; ++m_) \
        afr[m_] = *(const bf16x8*)(pT + aoff + m_ * 2048 + ch0); \
    __builtin_amdgcn_sched_barrier(0); \
    if (DOSTAGE) { \
        char* d_ = ldsw + sb * 32768; \
        gload_lds16(pa0, d_ + dA0); gload_lds16(pa1, d_ + dA1); \
        pa0 += 64; pa1 += 64; \
    } \
    __builtin_amdgcn_sched_barrier(0); \
    __builtin_amdgcn_s_barrier(); \
    asm volatile("s_waitcnt lgkmcnt(0)" ::: "memory"); \
    __builtin_amdgcn_sched_barrier(0); \
    __builtin_amdgcn_s_setprio(1); \
    MFMA8(afr, bfr) \
    __builtin_amdgcn_s_setprio(0); \
    __builtin_amdgcn_s_barrier(); \
  }

#define PH_B(DOSTAGE, GATE) \
  { \
    const char* pT = ldsc + cb * 32768; \
    _Pragma("unroll") for (int n_ = 0; n_ < 2; ++n_) \
        bgr[n_] = *(const bf16x8*)(pT + boff + n_ * 2048 + ch1); \
    _Pragma("unroll") for (int m_ = 0; m_ < 4; ++m_) \
        agr[m_] = *(const bf16x8*)(pT + aoff + m_ * 2048 + ch1); \
    __builtin_amdgcn_sched_barrier(0); \
    if (DOSTAGE) { \
        char* d_ = ldsw + sb * 32768; \
        gload_lds16(pb0, d_ + dB0); gload_lds16(pb1, d_ + dB1); \
        pb0 += 64; pb1 += 64; sb = (sb == 4) ? 0 : sb + 1; \
    } \
    GATE \
    __builtin_amdgcn_sched_barrier(0); \
    __builtin_amdgcn_s_barrier(); \
    asm volatile("s_waitcnt lgkmcnt(0)" ::: "memory"); \
    __builtin_amdgcn_sched_barrier(0); \
    __builtin_amdgcn_s_setprio(1); \
    MFMA8(agr, bgr) \
    __builtin_amdgcn_s_setprio(0); \
    __builtin_amdgcn_s_barrier(); \
    cb = (cb == 4) ? 0 : cb + 1; \
  }

#define KLOOP \
    bf16x8 afr[4], bfr[2], agr[4], bgr[2]; \
    int cb = 0; \
    STAGE(); STAGE(); STAGE(); STAGE(); \
    asm volatile("s_waitcnt vmcnt(12)" ::: "memory"); \
    __builtin_amdgcn_s_barrier(); \
    for (int T = 0; T < 60; ++T) { PH_A(1) PH_B(1, GATE12) } \
    PH_A(0) PH_B(0, GATE8) \
    PH_A(0) PH_B(0, GATE4) \
    PH_A(0) PH_B(0, GATE0) \
    PH_A(0) PH_B(0, GATEN)

// ---------------- GEMM1: act = silu(gate)*up, h = xb @ Wgu^T ----------------
// tile 256 tokens x 256 weight rows (=128 inter-cols). grid 2304 = 32 nb x 72 mb
__global__ void __launch_bounds__(512, 2)
k_g1(const unsigned short* __restrict__ xb, const unsigned short* __restrict__ wgu_b,
     const int* __restrict__ ptok, const int* __restrict__ seg,
     unsigned short* __restrict__ act) {
    extern __shared__ char smem[];
    char* ldsw = smem; const char* ldsc = smem;
    int logical = xcd_logical(blockIdx.x, 2304);
    int nb = logical / MT2, mb = logical % MT2;
    if (mb * BMT >= seg[8]) return;
    int e = 0;
    #pragma unroll
    for (int j = 1; j < 8; ++j) if (seg[j] <= mb * BMT) e = j;
    int tid = threadIdx.x, w = tid >> 6, l = tid & 63;
    int wr = w >> 2, wc = w & 3;

    // ---- staging: 4 gloads/thread/slot (A rows r0,r1; B rows r0,r1) ----
    int g = (l & 3) ^ ((l >> 2) & 3);            // pre-swizzled source chunk (r&3 swz)
    int r0 = w * 16 + (l >> 2), r1 = 128 + r0;   // rows within tile
    int t0 = ptok[mb * BMT + r0]; if (t0 < 0) t0 = 0;
    int t1 = ptok[mb * BMT + r1]; if (t1 < 0) t1 = 0;
    const char* pa0 = (const char*)xb + (size_t)t0 * 4096 + g * 16;
    const char* pa1 = (const char*)xb + (size_t)t1 * 4096 + g * 16;
    // B rows: per wc-64-block, j<32 gate / j>=32 up
    int j0 = r0 & 63, j1 = r1 & 63;
    int gr0 = (j0 < 32) ? (nb * 128 + (r0 >> 6) * 32 + j0)
                        : (D_INT + nb * 128 + (r0 >> 6) * 32 + j0 - 32);
    int gr1 = (j1 < 32) ? (nb * 128 + (r1 >> 6) * 32 + j1)
                        : (D_INT + nb * 128 + (r1 >> 6) * 32 + j1 - 32);
    const char* wbase = (const char*)wgu_b + (size_t)e * 8192 * 4096;
    const char* pb0 = wbase + (size_t)gr0 * 4096 + g * 16;
    const char* pb1 = wbase + (size_t)gr1 * 4096 + g * 16;
    int dA0 = w * 1024, dA1 = 8192 + w * 1024;
    int dB0 = 16384 + w * 1024, dB1 = 24576 + w * 1024;
    int sb = 0;
    auto STAGE = [&]() {
        char* d = ldsw + sb * 32768;
        gload_lds16(pa0, d + dA0); gload_lds16(pa1, d + dA1);
        gload_lds16(pb0, d + dB0); gload_lds16(pb1, d + dB1);
        pa0 += 64; pa1 += 64; pb0 += 64; pb1 += 64;
        sb = (sb == 4) ? 0 : sb + 1;
    };

    // ---- 32x32 frag read offsets (swizzled) ----
    int hi = l >> 5;
    int aoff = wr * 8192 + (l & 31) * 64;
    int boff = 16384 + wc * 4096 + (l & 31) * 64;
    int ch0 = ((hi) ^ (l & 3)) << 4;
    int ch1 = ((2 | hi) ^ (l & 3)) << 4;

    f32x16 acc[4][2];
    #pragma unroll
    for (int m = 0; m < 4; ++m)
        #pragma unroll
        for (int n = 0; n < 2; ++n) acc[m][n] = (f32x16)0.f;

    KLOOP

    // ---- epilogue: silu(gate)*up; acc[m][0]=gate, acc[m][1]=up ----
    int mbase = mb * BMT;
    int colg = nb * 128 + wc * 32 + (l & 31);
    #pragma unroll
    for (int m = 0; m < 4; ++m) {
        #pragma unroll
        for (int reg = 0; reg < 16; ++reg) {
            int rowl = wr * 128 + m * 32 + (reg & 3) + 8 * (reg >> 2) + 4 * hi;
            float gv = acc[m][0][reg], uv = acc[m][1][reg];
            float av = gv / (1.f + __expf(-gv)) * uv;
            act[(size_t)(mbase + rowl) * D_INT + colg] = f2bf(av);
        }
    }
}

// ---------------- GEMM2: out[tok] += wt * (act @ Wd^T), K-split 2 ----------------
// tile 256 tokens x 256 out-cols. grid 1152 = (8 nb x 2 ks) x 72 mb
__global__ void __launch_bounds__(512, 2)
k_g2(const unsigned short* __restrict__ act, const unsigned short* __restrict__ wd_b,
     const int* __restrict__ ptok, const float* __restrict__ pwt,
     const int* __restrict__ seg, float* __restrict__ out) {
    extern __shared__ char smem[];
    char* ldsw = smem; const char* ldsc = smem;
    int logical = xcd_logical(blockIdx.x, 1152);
    int pair = logical / MT2, mb = logical % MT2;
    int nb = pair >> 1, ks = pair & 1;
    if (mb * BMT >= seg[8]) return;
    int e = 0;
    #pragma unroll
    for (int j = 1; j < 8; ++j) if (seg[j] <= mb * BMT) e = j;
    int tid = threadIdx.x, w = tid >> 6, l = tid & 63;
    int wr = w >> 2, wc = w & 3;
    int koff = ks * 4096;                          // byte offset of K half (2048 elems)

    int g = (l & 3) ^ ((l >> 2) & 3);
    int r0 = w * 16 + (l >> 2), r1 = 128 + r0;
    const char* pa0 = (const char*)act + (size_t)(mb * BMT + r0) * 8192 + koff + g * 16;
    const char* pa1 = (const char*)act + (size_t)(mb * BMT + r1) * 8192 + koff + g * 16;
    const char* wbase = (const char*)wd_b + (size_t)e * D_HID * 8192;
    const char* pb0 = wbase + (size_t)(nb * 256 + r0) * 8192 + koff + g * 16;
    const char* pb1 = wbase + (size_t)(nb * 256 + r1) * 8192 + koff + g * 16;
    int dA0 = w * 1024, dA1 = 8192 + w * 1024;
    int dB0 = 16384 + w * 1024, dB1 = 24576 + w * 1024;
    int sb = 0;
    auto STAGE = [&]() {
        char* d = ldsw + sb * 32768;
        gload_lds16(pa0, d + dA0); gload_lds16(pa1, d + dA1);
        gload_lds16(pb0, d + dB0); gload_lds16(pb1, d + dB1);
        pa0 += 64; pa1 += 64; pb0 += 64; pb1 += 64;
        sb = (sb == 4) ? 0 : sb + 1;
    };

    int hi = l >> 5;
    int aoff = wr * 8192 + (l & 31) * 64;
    int boff = 16384 + wc * 4096 + (l & 31) * 64;
    int ch0 = ((hi) ^ (l & 3)) << 4;
    int ch1 = ((2 | hi) ^ (l & 3)) << 4;

    f32x16 acc[4][2];
    #pragma unroll
    for (int m = 0; m < 4; ++m)
        #pragma unroll
        for (int n = 0; n < 2; ++n) acc[m][n] = (f32x16)0.f;

    KLOOP

    // ---- epilogue: scaled atomic accumulate ----
    #pragma unroll
    for (int m = 0; m < 4; ++m) {
        #pragma unroll
        for (int reg = 0; reg < 16; ++reg) {
            int p = mb * BMT + wr * 128 + m * 32 + (reg & 3) + 8 * (reg >> 2) + 4 * hi;
            int tok = ptok[p];
            float wt = pwt[p];
            if (tok >= 0) {
                #pragma unroll
                for (int nf = 0; nf < 2; ++nf) {
                    int col = nb * 256 + wc * 64 + nf * 32 + (l & 31);
                    unsafeAtomicAdd(&out[(size_t)tok * D_HID + col], wt * acc[m][nf][reg]);
                }
            }
        }
    }
}

extern "C" void kernel_launch(void* const* d_in, const int* in_sizes, int n_in,
                              void* d_out, int out_size, void* d_ws, size_t ws_size,
                              hipStream_t stream) {
    const float* x   = (const float*)d_in[0];
    const float* tw  = (const float*)d_in[2];
    const int*   te  = (const int*)d_in[3];
    const float* wgu = (const float*)d_in[4];
    const float* wd  = (const float*)d_in[5];
    float* out = (float*)d_out;
    char*  ws  = (char*)d_ws;

    int*   ptok   = (int*)(ws + OFF_PTOK);
    float* pwt    = (float*)(ws + OFF_PWT);
    int*   counts = (int*)(ws + OFF_CNT);
    int*   toff   = (int*)(ws + OFF_TOFF);
    int*   seg    = (int*)(ws + OFF_SEG);
    unsigned short* xb  = (unsigned short*)(ws + OFF_XB);
    unsigned short* act = (unsigned short*)(ws + OFF_ACT);
    unsigned short* w_b = (unsigned short*)(ws + OFF_W);   // wgu_b, then reused for wd_b

    hipFuncSetAttribute((const void*)k_g1, hipFuncAttributeMaxDynamicSharedMemorySize, 163840);
    hipFuncSetAttribute((const void*)k_g2, hipFuncAttributeMaxDynamicSharedMemorySize, 163840);

    k_prep<<<2048, 256, 0, stream>>>(x, xb, out);
    k_count<<<N_EXP, 256, 0, stream>>>(te, counts, toff);
    k_fill<<<N_EXP, 256, 0, stream>>>(te, tw, counts, toff, ptok, pwt, seg);

    // wgu -> bf16 (33,554,432 float4), GEMM1
    k_cast<<<2048, 256, 0, stream>>>(wgu, w_b, 33554432);
    k_g1<<<2304, 512, 163840, stream>>>(xb, w_b, ptok, seg, act);
    // wd -> bf16 (16,777,216 float4, reuse buffer), GEMM2
    k_cast<<<2048, 256, 0, stream>>>(wd, w_b, 16777216);
    k_g2<<<1152, 512, 163840, stream>>>(act, w_b, ptok, pwt, seg, out);
}

// Round 10
// 1410.669 us; speedup vs baseline: 1.0815x; 1.0815x over previous
//
#include <hip/hip_runtime.h>
#include <stdint.h>

// ---------------- problem constants ----------------
#define T_TOKENS 4096
#define D_HID    2048
#define D_INT    4096
#define N_EXP    8
#define TOPK     4
#define NFLAT    (T_TOKENS*TOPK)      // 16384 routed pairs
#define BMT      256                  // M tile
#define MAXPAD   (NFLAT + N_EXP*BMT)  // 18432 worst-case padded rows
#define MT2      (MAXPAD/BMT)         // 72 M-tiles

// ---------------- ws layout (bytes) ----------------
#define OFF_PTOK 0ull
#define OFF_PWT  73728ull
#define OFF_CNT  147456ull
#define OFF_TOFF 147712ull
#define OFF_SEG  155904ull
#define OFF_XB   262144ull                  // 4096*2048*2 = 16,777,216
#define OFF_ACT  17039360ull                // 18432*4096*2 = 150,994,944
#define OFF_W    168034304ull               // wgu_b 268,435,456 (wd_b overlay in fallback)
#define OFF_WD2  436469760ull               // separate wd_b region (fold-in path)
#define NEED_FOLD 570687488ull              // OFF_WD2 + 134,217,728

typedef float f32x4   __attribute__((ext_vector_type(4)));
typedef float f32x16  __attribute__((ext_vector_type(16)));
typedef short bf16x8  __attribute__((ext_vector_type(8)));

__device__ __forceinline__ unsigned short f2bf(float f) {
    unsigned int u = __float_as_uint(f);
    u += 0x7fffu + ((u >> 16) & 1u);      // RNE
    return (unsigned short)(u >> 16);
}

__device__ __forceinline__ void gload_lds16(const void* g, void* l) {
    __builtin_amdgcn_global_load_lds((const __attribute__((address_space(1))) void*)g,
                                     (__attribute__((address_space(3))) void*)l,
                                     16, 0, 0);
}

// XCD-bijective chunk swizzle (m204)
__device__ __forceinline__ int xcd_logical(int hw, int nwg) {
    int q = nwg >> 3, r = nwg & 7;
    int xc = hw & 7, sl = hw >> 3;
    return (xc < r ? xc * (q + 1) : r * (q + 1) + (xc - r) * q) + sl;
}

// ---------------- prep: cast x -> bf16 + zero out (grid-stride) ----------------
__global__ void k_prep(const float* __restrict__ x, unsigned short* __restrict__ xb,
                       float* __restrict__ out) {
    const int N4 = T_TOKENS * D_HID / 4;             // 2,097,152
    for (int i = blockIdx.x * 256 + threadIdx.x; i < N4; i += 2048 * 256) {
        float4 v = ((const float4*)x)[i];
        ushort4 h;
        h.x = f2bf(v.x); h.y = f2bf(v.y); h.z = f2bf(v.z); h.w = f2bf(v.w);
        ((ushort4*)xb)[i] = h;
        ((float4*)out)[i] = make_float4(0.f, 0.f, 0.f, 0.f);
    }
}

// ---------------- fp32 -> bf16 cast (grid-stride, n4 float4s) ----------------
__global__ void k_cast(const float* __restrict__ src, unsigned short* __restrict__ dst, int n4) {
    for (int i = blockIdx.x * 256 + threadIdx.x; i < n4; i += 2048 * 256) {
        float4 v = ((const float4*)src)[i];
        ushort4 h;
        h.x = f2bf(v.x); h.y = f2bf(v.y); h.z = f2bf(v.z); h.w = f2bf(v.w);
        ((ushort4*)dst)[i] = h;
    }
}

// ---------------- routing: deterministic compaction ----------------
__global__ void k_count(const int* __restrict__ te, int* __restrict__ counts,
                        int* __restrict__ toff) {
    int e = blockIdx.x, t = threadIdx.x;
    int cnt = 0;
    int base = t * 64;
    for (int i = 0; i < 64; i++) cnt += (te[base + i] == e);
    __shared__ int s[256];
    s[t] = cnt; __syncthreads();
    int incl = cnt;
    for (int off = 1; off < 256; off <<= 1) {
        int tmp = (t >= off) ? s[t - off] : 0;
        __syncthreads();
        incl += tmp; s[t] = incl;
        __syncthreads();
    }
    toff[e * 256 + t] = incl - cnt;
    if (t == 255) counts[e] = incl;
}

__global__ void k_fill(const int* __restrict__ te, const float* __restrict__ tw,
                       const int* __restrict__ counts, const int* __restrict__ toff,
                       int* __restrict__ ptok, float* __restrict__ pwt, int* __restrict__ seg) {
    int e = blockIdx.x, t = threadIdx.x;
    int segs[9]; int a = 0;
    #pragma unroll
    for (int j = 0; j < 8; j++) { segs[j] = a; a += (counts[j] + BMT - 1) & ~(BMT - 1); }
    segs[8] = a;
    if (e == 0 && t == 0) { for (int j = 0; j < 9; j++) seg[j] = segs[j]; }
    int base = segs[e] + toff[e * 256 + t];
    int rank = 0;
    for (int i = t * 64; i < (t + 1) * 64; i++) {
        if (te[i] == e) { ptok[base + rank] = i >> 2; pwt[base + rank] = tw[i]; rank++; }
    }
    int cnt = counts[e], pc = (cnt + BMT - 1) & ~(BMT - 1);
    for (int i = cnt + t; i < pc; i += 256) { ptok[segs[e] + i] = -1; pwt[segs[e] + i] = 0.f; }
}

// =====================================================================
// Round-10 core: 32x32x16 MFMA + 5-slot ring, with CORRECTED swizzle.
// Swizzle derivation (fixes r9's 1.6e8 bank conflicts): row stride is
// 64B = 16 banks, so row parity selects the bank half and the 16B-chunk
// must cycle with (r>>1)&3. Phys chunk p of row r holds data chunk
// p ^ ((r>>1)&3). Stage: lane l writes phys l&3, row bits give
// (r>>1)&3 = (l>>3)&3 -> src chunk g=(l&3)^((l>>3)&3) (identical to
// the r8 formula that measured 0 conflicts). Read: data chunk (2kk+hi)
// -> phys ((2kk+hi) ^ ((l>>1)&3)). Consecutive 8 lanes then cover all
// 32 banks exactly once (even rows quads of 0-15, odd rows 16-31).
// Everything else as r9: 256x256 tile, 8 waves, wave C=128x64 as 4x2
// 32x32 frags, slot=32KiB, 5 slots=160 KiB, distance 4,
// vmcnt gates 12/12/8/4/0, per-phase [6 reads][stage][BAR][lgkm0]
// [prio1 8 MFMA prio0][BAR].
// =====================================================================

#define MFMA8(AV, BV) \
    _Pragma("unroll") for (int m_ = 0; m_ < 4; ++m_) \
      _Pragma("unroll") for (int n_ = 0; n_ < 2; ++n_) \
        acc[m_][n_] = __builtin_amdgcn_mfma_f32_32x32x16_bf16(AV[m_], BV[n_], acc[m_][n_], 0, 0, 0);

#define GATE12 asm volatile("s_waitcnt vmcnt(12)" ::: "memory");
#define GATE8  asm volatile("s_waitcnt vmcnt(8)" ::: "memory");
#define GATE4  asm volatile("s_waitcnt vmcnt(4)" ::: "memory");
#define GATE0  asm volatile("s_waitcnt vmcnt(0)" ::: "memory");
#define GATEN

#define PH_A(DOSTAGE) \
  { \
    const char* pT = ldsc + cb * 32768; \
    _Pragma("unroll") for (int n_ = 0; n_ < 2; ++n_) \
        bfr[n_] = *(const bf16x8*)(pT + boff + n_ * 2048 + ch0); \
    _Pragma("unroll") for (int m_ = 0; m_ < 4; ++m_) \
        afr[m_] = *(const bf16x8*)(pT + aoff + m_ * 2048 + ch0); \
    __builtin_amdgcn_sched_barrier(0); \
    if (DOSTAGE) { \
        char* d_ = ldsw + sb * 32768; \
        gload_lds16(pa0, d_ + dA0); gload_lds16(pa1, d_ + dA1); \
        pa0 += 64; pa1 += 64; \
    } \
    __builtin_amdgcn_sched_barrier(0); \
    __builtin_amdgcn_s_barrier(); \
    asm volatile("s_waitcnt lgkmcnt(0)" ::: "memory"); \
    __builtin_amdgcn_sched_barrier(0); \
    __builtin_amdgcn_s_setprio(1); \
    MFMA8(afr, bfr) \
    __builtin_amdgcn_s_setprio(0); \
    __builtin_amdgcn_s_barrier(); \
  }

#define PH_B(DOSTAGE, GATE) \
  { \
    const char* pT = ldsc + cb * 32768; \
    _Pragma("unroll") for (int n_ = 0; n_ < 2; ++n_) \
        bgr[n_] = *(const bf16x8*)(pT + boff + n_ * 2048 + ch1); \
    _Pragma("unroll") for (int m_ = 0; m_ < 4; ++m_) \
        agr[m_] = *(const bf16x8*)(pT + aoff + m_ * 2048 + ch1); \
    __builtin_amdgcn_sched_barrier(0); \
    if (DOSTAGE) { \
        char* d_ = ldsw + sb * 32768; \
        gload_lds16(pb0, d_ + dB0); gload_lds16(pb1, d_ + dB1); \
        pb0 += 64; pb1 += 64; sb = (sb == 4) ? 0 : sb + 1; \
    } \
    GATE \
    __builtin_amdgcn_sched_barrier(0); \
    __builtin_amdgcn_s_barrier(); \
    asm volatile("s_waitcnt lgkmcnt(0)" ::: "memory"); \
    __builtin_amdgcn_sched_barrier(0); \
    __builtin_amdgcn_s_setprio(1); \
    MFMA8(agr, bgr) \
    __builtin_amdgcn_s_setprio(0); \
    __builtin_amdgcn_s_barrier(); \
    cb = (cb == 4) ? 0 : cb + 1; \
  }

#define KLOOP \
    bf16x8 afr[4], bfr[2], agr[4], bgr[2]; \
    int cb = 0; \
    STAGE(); STAGE(); STAGE(); STAGE(); \
    asm volatile("s_waitcnt vmcnt(12)" ::: "memory"); \
    __builtin_amdgcn_s_barrier(); \
    for (int T = 0; T < 60; ++T) { PH_A(1) PH_B(1, GATE12) } \
    PH_A(0) PH_B(0, GATE8) \
    PH_A(0) PH_B(0, GATE4) \
    PH_A(0) PH_B(0, GATE0) \
    PH_A(0) PH_B(0, GATEN)

// ---------------- GEMM1: act = silu(gate)*up, h = xb @ Wgu^T ----------------
// tile 256 tokens x 256 weight rows (=128 inter-cols). grid 2304 = 32 nb x 72 mb
// Also absorbs the wd fp32->bf16 cast (ncast4 float4s, grid-stride) under
// its compute (g1 is at only ~19% HBM; ~402 MB hides).
__global__ void __launch_bounds__(512, 2)
k_g1(const unsigned short* __restrict__ xb, const unsigned short* __restrict__ wgu_b,
     const int* __restrict__ ptok, const int* __restrict__ seg,
     unsigned short* __restrict__ act,
     const float4* __restrict__ wdsrc, ushort4* __restrict__ wddst, int ncast4) {
    extern __shared__ char smem[];
    char* ldsw = smem; const char* ldsc = smem;

    // ---- absorbed wd cast (before early-exit so every block contributes) ----
    for (size_t i = (size_t)blockIdx.x * 512 + threadIdx.x; i < (size_t)ncast4;
         i += (size_t)2304 * 512) {
        float4 v = wdsrc[i];
        ushort4 h;
        h.x = f2bf(v.x); h.y = f2bf(v.y); h.z = f2bf(v.z); h.w = f2bf(v.w);
        wddst[i] = h;
    }
    __builtin_amdgcn_sched_barrier(0);

    int logical = xcd_logical(blockIdx.x, 2304);
    int nb = logical / MT2, mb = logical % MT2;
    if (mb * BMT >= seg[8]) return;
    int e = 0;
    #pragma unroll
    for (int j = 1; j < 8; ++j) if (seg[j] <= mb * BMT) e = j;
    int tid = threadIdx.x, w = tid >> 6, l = tid & 63;
    int wr = w >> 2, wc = w & 3;

    // ---- staging: 4 gloads/thread/slot; src chunk g = (l&3)^((l>>3)&3) ----
    int g = (l & 3) ^ ((l >> 3) & 3);
    int r0 = w * 16 + (l >> 2), r1 = 128 + r0;   // rows within tile
    int t0 = ptok[mb * BMT + r0]; if (t0 < 0) t0 = 0;
    int t1 = ptok[mb * BMT + r1]; if (t1 < 0) t1 = 0;
    const char* pa0 = (const char*)xb + (size_t)t0 * 4096 + g * 16;
    const char* pa1 = (const char*)xb + (size_t)t1 * 4096 + g * 16;
    // B rows: per wc-64-block, j<32 gate / j>=32 up
    int j0 = r0 & 63, j1 = r1 & 63;
    int gr0 = (j0 < 32) ? (nb * 128 + (r0 >> 6) * 32 + j0)
                        : (D_INT + nb * 128 + (r0 >> 6) * 32 + j0 - 32);
    int gr1 = (j1 < 32) ? (nb * 128 + (r1 >> 6) * 32 + j1)
                        : (D_INT + nb * 128 + (r1 >> 6) * 32 + j1 - 32);
    const char* wbase = (const char*)wgu_b + (size_t)e * 8192 * 4096;
    const char* pb0 = wbase + (size_t)gr0 * 4096 + g * 16;
    const char* pb1 = wbase + (size_t)gr1 * 4096 + g * 16;
    int dA0 = w * 1024, dA1 = 8192 + w * 1024;
    int dB0 = 16384 + w * 1024, dB1 = 24576 + w * 1024;
    int sb = 0;
    auto STAGE = [&]() {
        char* d = ldsw + sb * 32768;
        gload_lds16(pa0, d + dA0); gload_lds16(pa1, d + dA1);
        gload_lds16(pb0, d + dB0); gload_lds16(pb1, d + dB1);
        pa0 += 64; pa1 += 64; pb0 += 64; pb1 += 64;
        sb = (sb == 4) ? 0 : sb + 1;
    };

    // ---- 32x32 frag read offsets (corrected swizzle) ----
    int hi = l >> 5;
    int sw = (l >> 1) & 3;                       // (row>>1)&3, row = l&31
    int aoff = wr * 8192 + (l & 31) * 64;
    int boff = 16384 + wc * 4096 + (l & 31) * 64;
    int ch0 = (hi ^ sw) << 4;
    int ch1 = ((2 | hi) ^ sw) << 4;

    f32x16 acc[4][2];
    #pragma unroll
    for (int m = 0; m < 4; ++m)
        #pragma unroll
        for (int n = 0; n < 2; ++n) acc[m][n] = (f32x16)0.f;

    KLOOP

    // ---- epilogue: silu(gate)*up; acc[m][0]=gate, acc[m][1]=up ----
    int mbase = mb * BMT;
    int colg = nb * 128 + wc * 32 + (l & 31);
    #pragma unroll
    for (int m = 0; m < 4; ++m) {
        #pragma unroll
        for (int reg = 0; reg < 16; ++reg) {
            int rowl = wr * 128 + m * 32 + (reg & 3) + 8 * (reg >> 2) + 4 * hi;
            float gv = acc[m][0][reg], uv = acc[m][1][reg];
            float av = gv / (1.f + __expf(-gv)) * uv;
            act[(size_t)(mbase + rowl) * D_INT + colg] = f2bf(av);
        }
    }
}

// ---------------- GEMM2: out[tok] += wt * (act @ Wd^T), K-split 2 ----------------
// tile 256 tokens x 256 out-cols. grid 1152 = (8 nb x 2 ks) x 72 mb
__global__ void __launch_bounds__(512, 2)
k_g2(const unsigned short* __restrict__ act, const unsigned short* __restrict__ wd_b,
     const int* __restrict__ ptok, const float* __restrict__ pwt,
     const int* __restrict__ seg, float* __restrict__ out) {
    extern __shared__ char smem[];
    char* ldsw = smem; const char* ldsc = smem;
    int logical = xcd_logical(blockIdx.x, 1152);
    int pair = logical / MT2, mb = logical % MT2;
    int nb = pair >> 1, ks = pair & 1;
    if (mb * BMT >= seg[8]) return;
    int e = 0;
    #pragma unroll
    for (int j = 1; j < 8; ++j) if (seg[j] <= mb * BMT) e = j;
    int tid = threadIdx.x, w = tid >> 6, l = tid & 63;
    int wr = w >> 2, wc = w & 3;
    int koff = ks * 4096;                          // byte offset of K half (2048 elems)

    int g = (l & 3) ^ ((l >> 3) & 3);
    int r0 = w * 16 + (l >> 2), r1 = 128 + r0;
    const char* pa0 = (const char*)act + (size_t)(mb * BMT + r0) * 8192 + koff + g * 16;
    const char* pa1 = (const char*)act + (size_t)(mb * BMT + r1) * 8192 + koff + g * 16;
    const char* wbase = (const char*)wd_b + (size_t)e * D_HID * 8192;
    const char* pb0 = wbase + (size_t)(nb * 256 + r0) * 8192 + koff + g * 16;
    const char* pb1 = wbase + (size_t)(nb * 256 + r1) * 8192 + koff + g * 16;
    int dA0 = w * 1024, dA1 = 8192 + w * 1024;
    int dB0 = 16384 + w * 1024, dB1 = 24576 + w * 1024;
    int sb = 0;
    auto STAGE = [&]() {
        char* d = ldsw + sb * 32768;
        gload_lds16(pa0, d + dA0); gload_lds16(pa1, d + dA1);
        gload_lds16(pb0, d + dB0); gload_lds16(pb1, d + dB1);
        pa0 += 64; pa1 += 64; pb0 += 64; pb1 += 64;
        sb = (sb == 4) ? 0 : sb + 1;
    };

    int hi = l >> 5;
    int sw = (l >> 1) & 3;
    int aoff = wr * 8192 + (l & 31) * 64;
    int boff = 16384 + wc * 4096 + (l & 31) * 64;
    int ch0 = (hi ^ sw) << 4;
    int ch1 = ((2 | hi) ^ sw) << 4;

    f32x16 acc[4][2];
    #pragma unroll
    for (int m = 0; m < 4; ++m)
        #pragma unroll
        for (int n = 0; n < 2; ++n) acc[m][n] = (f32x16)0.f;

    KLOOP

    // ---- epilogue: scaled atomic accumulate ----
    #pragma unroll
    for (int m = 0; m < 4; ++m) {
        #pragma unroll
        for (int reg = 0; reg < 16; ++reg) {
            int p = mb * BMT + wr * 128 + m * 32 + (reg & 3) + 8 * (reg >> 2) + 4 * hi;
            int tok = ptok[p];
            float wt = pwt[p];
            if (tok >= 0) {
                #pragma unroll
                for (int nf = 0; nf < 2; ++nf) {
                    int col = nb * 256 + wc * 64 + nf * 32 + (l & 31);
                    unsafeAtomicAdd(&out[(size_t)tok * D_HID + col], wt * acc[m][nf][reg]);
                }
            }
        }
    }
}

extern "C" void kernel_launch(void* const* d_in, const int* in_sizes, int n_in,
                              void* d_out, int out_size, void* d_ws, size_t ws_size,
                              hipStream_t stream) {
    const float* x   = (const float*)d_in[0];
    const float* tw  = (const float*)d_in[2];
    const int*   te  = (const int*)d_in[3];
    const float* wgu = (const float*)d_in[4];
    const float* wd  = (const float*)d_in[5];
    float* out = (float*)d_out;
    char*  ws  = (char*)d_ws;

    int*   ptok   = (int*)(ws + OFF_PTOK);
    float* pwt    = (float*)(ws + OFF_PWT);
    int*   counts = (int*)(ws + OFF_CNT);
    int*   toff   = (int*)(ws + OFF_TOFF);
    int*   seg    = (int*)(ws + OFF_SEG);
    unsigned short* xb    = (unsigned short*)(ws + OFF_XB);
    unsigned short* act   = (unsigned short*)(ws + OFF_ACT);
    unsigned short* wgu_b = (unsigned short*)(ws + OFF_W);

    bool fold = (ws_size >= NEED_FOLD);
    unsigned short* wd_b = fold ? (unsigned short*)(ws + OFF_WD2) : wgu_b;

    hipFuncSetAttribute((const void*)k_g1, hipFuncAttributeMaxDynamicSharedMemorySize, 163840);
    hipFuncSetAttribute((const void*)k_g2, hipFuncAttributeMaxDynamicSharedMemorySize, 163840);

    k_prep<<<2048, 256, 0, stream>>>(x, xb, out);
    k_count<<<N_EXP, 256, 0, stream>>>(te, counts, toff);
    k_fill<<<N_EXP, 256, 0, stream>>>(te, tw, counts, toff, ptok, pwt, seg);

    // wgu -> bf16 (33,554,432 float4), then GEMM1 (absorbing wd cast if room)
    k_cast<<<2048, 256, 0, stream>>>(wgu, wgu_b, 33554432);
    k_g1<<<2304, 512, 163840, stream>>>(xb, wgu_b, ptok, seg, act,
                                        (const float4*)wd, (ushort4*)wd_b,
                                        fold ? 16777216 : 0);
    if (!fold) k_cast<<<2048, 256, 0, stream>>>(wd, wd_b, 16777216);
    k_g2<<<1152, 512, 163840, stream>>>(act, wd_b, ptok, pwt, seg, out);
}